// Round 3
// baseline (3959.626 us; speedup 1.0000x reference)
//
#include <hip/hip_runtime.h>
#include <hip/hip_fp16.h>
#include <cstdint>

#define BATCH 256
#define SEQ   2048
#define IN_DIM 4
#define HID   256
#define G4    1024   // 4*HID

// ---------- types ----------
typedef _Float16 f16x8 __attribute__((ext_vector_type(8)));
typedef float    f32x4 __attribute__((ext_vector_type(4)));

union U4H8 { uint4 u; f16x8 h; };

__device__ __forceinline__ uint32_t pack_h2(float a, float b) {
    union { uint32_t u; __half2 hh; } v;
    v.hh = __floats2half2_rn(a, b);   // a -> lo, b -> hi
    return v.u;
}

__device__ __forceinline__ float sigmoidf_(float x) {
    return 1.0f / (1.0f + __expf(-x));
}
__device__ __forceinline__ float tanhf_(float x) {
    return 1.0f - 2.0f / (__expf(2.0f * x) + 1.0f);
}

// ---------- ws layout (bytes) ----------
// wfrag: 8 waves x 64 frags x 64 lanes x 16B = 524288
#define OFF_BIAS  524288
#define OFF_CONVF 528384
#define OFF_KSIM  529408
#define OFF_HOUT  530432

// ---------- prep: build MFMA A-fragments (fp16) + fused bias ----------
// Whh (1024x256 f32) -> per-(wave,frag,lane) uint4 A-fragments for
// v_mfma_f32_16x16x32_f16.
//   wave w owns rows [w*128, w*128+128); tile rt: rows w*128+rt*16+(0..15)
//   chunk c: k in [32c, 32c+32); frag f = rt*8 + c
//   A-frag: lane = (kblk=((k&31)>>3))*16 + (row&15); dword d = ((k&7)>>1)
//   dword packs (k even, k+1) as (lo,hi).
// B (h) is packed with the SAME (kblk,d) enumeration at runtime, so the
// hardware's internal k-order cancels (sum over k is permutation-invariant).
__global__ void prep_kernel(const float* __restrict__ Whh,
                            const float* __restrict__ bih,
                            const float* __restrict__ bhh,
                            uint32_t* __restrict__ wfrag,
                            float* __restrict__ bias) {
    int gid = blockIdx.x * blockDim.x + threadIdx.x;  // 0..131071
    int row = gid >> 7;      // 0..1023
    int pc  = gid & 127;     // pair-col (k0 = 2*pc)
    float a = Whh[row * HID + 2 * pc];
    float b = Whh[row * HID + 2 * pc + 1];
    uint32_t p = pack_h2(a, b);

    int w    = row >> 7;
    int rr   = row & 127;
    int rt   = rr >> 4;
    int lrow = rr & 15;
    int c    = pc >> 4;            // (2*pc)>>5
    int kk   = (2 * pc) & 31;      // k within chunk
    int bblk = kk >> 3;            // lane k-block 0..3
    int d    = (kk >> 1) & 3;      // dword 0..3
    int f    = rt * 8 + c;
    int lane = bblk * 16 + lrow;
    wfrag[(((w * 64 + f) * 64) + lane) * 4 + d] = p;

    if (gid < G4) bias[gid] = bih[gid] + bhh[gid];
}

// ---------- features: conv mean + RBF kernel sim ----------
__global__ void feat_kernel(const float* __restrict__ x,
                            const float* __restrict__ conv_w,
                            const float* __restrict__ conv_b,
                            float* __restrict__ convf,
                            float* __restrict__ ksim) {
    int b = blockIdx.x, t = threadIdx.x;  // 256 threads
    const float4* xb = (const float4*)(x + (size_t)b * SEQ * IN_DIM);
    float cw0 = conv_w[0], cw1 = conv_w[1], cw2 = conv_w[2], cw3 = conv_w[3];
    float cb = conv_b[0];
    float s_sig = 0.f, s_sq = 0.f;
#pragma unroll
    for (int k = 0; k < 8; ++k) {
        int s = t + k * 256;
        float4 v = xb[s];
        float d = v.x * cw0 + v.y * cw1 + v.z * cw2 + v.w * cw3 + cb;
        s_sig += sigmoidf_(d);
        s_sq  += v.x * v.x + v.y * v.y + v.z * v.z + v.w * v.w;
    }
    __shared__ float sA[256], sB[256];
    sA[t] = s_sig; sB[t] = s_sq;
    __syncthreads();
    for (int off = 128; off > 0; off >>= 1) {
        if (t < off) { sA[t] += sA[t + off]; sB[t] += sB[t + off]; }
        __syncthreads();
    }
    if (t == 0) {
        convf[b] = sA[0] * (1.0f / 2048.0f);
        ksim[b]  = __expf(-sB[0]);
    }
}

// ---------- LSTM recurrence: 1 sample per block, MFMA z = Whh*h ----------
// 512 threads = 8 waves (2/SIMD, 256 unified regs/wave). Wave w owns gate
// rows [w*128, w*128+128) as 8 tiles of 16 rows.
// Per step:
//   phase 1: 8 K-chunks x 8 tiles of v_mfma_f32_16x16x32_f16.
//     A: 45 frags/wave register-resident (AGPR/VGPR -> native MFMA operand,
//        no v_accvgpr bounces, unlike the dot2 designs R0-R2), 19 frags/wave
//        in LDS (152KB, read per step).
//     B: h broadcast into all 16 cols: lane l reads h-pairs
//        [16c + (l>>4)*4 .. +3] (ds_read_b128, 16-way broadcast) -> every
//        output column equals z, read col 0.
//   z-write: lanes (l&15)==0 hold z rows (l>>4)*4+reg (verified C/D map);
//     8 x ds_write_b128 -> zbuf[r] = z[r]. barrier.
//   phase 2: threads 0..255: unit u reads z[u+256g], adds bias+Wih*x_t (f32),
//     gates, thread-local c/h, writes h fp16. barrier.
#define LDSF_U4 (8 * 19 * 64)          // 9728 uint4 = 38912 dwords (152KB)
#define ZBUF_DW (LDSF_U4 * 4)          // 38912
#define HBUF0_DW (ZBUF_DW + 1024)      // 39936
#define HBUF1_DW (HBUF0_DW + 128)      // 40064
#define SMEM_DW  (HBUF1_DW + 128)      // 40192 dw = 160768 B (<= 163840)

__global__ __launch_bounds__(512, 2)
void recur_kernel(const float* __restrict__ x,
                  const float* __restrict__ Wih,
                  const uint4* __restrict__ wfrag,
                  const float* __restrict__ bias,
                  float* __restrict__ h_out) {
    extern __shared__ uint32_t smem[];
    uint4*    ldsf  = (uint4*)smem;            // [8][19][64] uint4
    float*    zbuf  = (float*)(smem + ZBUF_DW);// 1024 f32
    uint32_t* hbuf0 = smem + HBUF0_DW;         // 256 fp16
    uint32_t* hbuf1 = smem + HBUF1_DW;

    const int b = blockIdx.x;
    const int t = threadIdx.x;
    const int lane = t & 63;
    const int w = t >> 6;
    const int u = t & 255;

    // register-resident A-fragments (45/wave); rest staged to LDS (19/wave)
    uint4 afr[45];
#pragma unroll
    for (int f = 0; f < 45; ++f) afr[f] = wfrag[(w * 64 + f) * 64 + lane];
#pragma unroll
    for (int f = 0; f < 19; ++f)
        ldsf[(w * 19 + f) * 64 + lane] = wfrag[(w * 64 + 45 + f) * 64 + lane];
    if (t < 128) hbuf0[t] = 0u;   // h = 0

    // pin fragments (forbid per-step reloads from global)
#pragma unroll
    for (int f = 0; f < 45; ++f) {
        asm volatile("" : "+v"(afr[f].x), "+v"(afr[f].y),
                          "+v"(afr[f].z), "+v"(afr[f].w));
    }

    // epilogue state (threads 0..255 use it; uniform allocation)
    const float4 wv0 = ((const float4*)Wih)[u];
    const float4 wv1 = ((const float4*)Wih)[u + 256];
    const float4 wv2 = ((const float4*)Wih)[u + 512];
    const float4 wv3 = ((const float4*)Wih)[u + 768];
    const float bs0 = bias[u],       bs1 = bias[u + 256];
    const float bs2 = bias[u + 512], bs3 = bias[u + 768];

    float c_state = 0.f, h_last = 0.f;
    const float4* xb = (const float4*)(x + (size_t)b * SEQ * IN_DIM);

    __syncthreads();

    uint32_t* hr = hbuf0;
    uint32_t* hw = hbuf1;

    for (int s = 0; s < SEQ; ++s) {
        const float4 xt = xb[s];   // uniform; hidden under MFMA phase

        f32x4 acc[8];
#pragma unroll
        for (int rt = 0; rt < 8; ++rt) acc[rt] = (f32x4){0.f, 0.f, 0.f, 0.f};

        const char* hrb = (const char*)hr;
        const int boff = (lane >> 4) << 4;   // k-block byte offset
#pragma unroll
        for (int c = 0; c < 8; ++c) {
            U4H8 hb_;
            hb_.u = *(const uint4*)(hrb + c * 64 + boff);  // b128 broadcast
#pragma unroll
            for (int rt = 0; rt < 8; ++rt) {
                const int f = rt * 8 + c;   // constant after unroll
                U4H8 ab;
                if (f < 45) ab.u = afr[f];
                else        ab.u = ldsf[(w * 19 + (f - 45)) * 64 + lane];
                acc[rt] = __builtin_amdgcn_mfma_f32_16x16x32_f16(
                    ab.h, hb_.h, acc[rt], 0, 0, 0);
            }
        }

        // z-write: col-0 lanes hold rows (lane>>4)*4+reg of each tile
        if ((lane & 15) == 0) {
            const int q = lane >> 4;
#pragma unroll
            for (int rt = 0; rt < 8; ++rt) {
                *(f32x4*)(zbuf + w * 128 + rt * 16 + q * 4) = acc[rt];
            }
        }
        __syncthreads();

        if (t < 256) {
            float zi = zbuf[u]       + bs0 + xt.x*wv0.x + xt.y*wv0.y + xt.z*wv0.z + xt.w*wv0.w;
            float zf = zbuf[u + 256] + bs1 + xt.x*wv1.x + xt.y*wv1.y + xt.z*wv1.z + xt.w*wv1.w;
            float zg = zbuf[u + 512] + bs2 + xt.x*wv2.x + xt.y*wv2.y + xt.z*wv2.z + xt.w*wv2.w;
            float zo = zbuf[u + 768] + bs3 + xt.x*wv3.x + xt.y*wv3.y + xt.z*wv3.z + xt.w*wv3.w;
            const float ig = sigmoidf_(zi);
            const float fg = sigmoidf_(zf);
            const float gg = tanhf_(zg);
            const float og = sigmoidf_(zo);
            c_state = fg * c_state + ig * gg;
            h_last  = og * tanhf_(c_state);
            ((__half*)hw)[u] = __float2half_rn(h_last);
        }
        __syncthreads();
        uint32_t* tmp = hr; hr = hw; hw = tmp;
    }

    if (t < 256) h_out[b * HID + u] = h_last;
}

// ---------- head: fc + relu + out + softmax ----------
__global__ void head_kernel(const float* __restrict__ fc_w,
                            const float* __restrict__ fc_b,
                            const float* __restrict__ out_w,
                            const float* __restrict__ out_b,
                            const float* __restrict__ convf,
                            const float* __restrict__ ksim,
                            const float* __restrict__ h_out,
                            float* __restrict__ out) {
    int b = blockIdx.x, j = threadIdx.x;  // 256 threads
    const float* hrow = h_out + b * HID;
    const float* w = fc_w + j * (HID + 2);
    float acc = fc_b[j] + w[0] * convf[b] + w[HID + 1] * ksim[b];
#pragma unroll 8
    for (int k = 0; k < HID; ++k) acc += w[1 + k] * hrow[k];
    float hid = fmaxf(acc, 0.f);
    __shared__ float r0[256], r1[256];
    r0[j] = hid * out_w[j];
    r1[j] = hid * out_w[HID + j];
    __syncthreads();
    for (int off = 128; off > 0; off >>= 1) {
        if (j < off) { r0[j] += r0[j + off]; r1[j] += r1[j + off]; }
        __syncthreads();
    }
    if (j == 0) {
        float l0 = r0[0] + out_b[0];
        float l1 = r1[0] + out_b[1];
        float m = fmaxf(l0, l1);
        float e0 = __expf(l0 - m), e1 = __expf(l1 - m);
        float inv = 1.0f / (e0 + e1);
        out[b * 2 + 0] = e0 * inv;
        out[b * 2 + 1] = e1 * inv;
    }
}

// ---------- launch ----------
extern "C" void kernel_launch(void* const* d_in, const int* in_sizes, int n_in,
                              void* d_out, int out_size, void* d_ws, size_t ws_size,
                              hipStream_t stream) {
    const float* x      = (const float*)d_in[0];
    const float* conv_w = (const float*)d_in[1];
    const float* conv_b = (const float*)d_in[2];
    const float* Wih    = (const float*)d_in[3];
    const float* Whh    = (const float*)d_in[4];
    const float* bih    = (const float*)d_in[5];
    const float* bhh    = (const float*)d_in[6];
    const float* fcw    = (const float*)d_in[7];
    const float* fcb    = (const float*)d_in[8];
    const float* outw   = (const float*)d_in[9];
    const float* outb   = (const float*)d_in[10];
    float* out = (float*)d_out;

    uint8_t* ws = (uint8_t*)d_ws;
    uint32_t* wfrag = (uint32_t*)ws;
    float* bias  = (float*)(ws + OFF_BIAS);
    float* convf = (float*)(ws + OFF_CONVF);
    float* ksim  = (float*)(ws + OFF_KSIM);
    float* h_out = (float*)(ws + OFF_HOUT);

    prep_kernel<<<512, 256, 0, stream>>>(Whh, bih, bhh, wfrag, bias);
    feat_kernel<<<BATCH, 256, 0, stream>>>(x, conv_w, conv_b, convf, ksim);

    const size_t smem_bytes = (size_t)SMEM_DW * 4;  // 160768 B
    hipFuncSetAttribute((const void*)recur_kernel,
                        hipFuncAttributeMaxDynamicSharedMemorySize, (int)smem_bytes);
    recur_kernel<<<BATCH, 512, smem_bytes, stream>>>(
        x, Wih, (const uint4*)wfrag, bias, h_out);

    head_kernel<<<BATCH, 256, 0, stream>>>(fcw, fcb, outw, outb, convf, ksim, h_out, out);
}

// Round 4
// 3746.998 us; speedup vs baseline: 1.0567x; 1.0567x over previous
//
#include <hip/hip_runtime.h>
#include <hip/hip_fp16.h>
#include <cstdint>

#define BATCH 256
#define SEQ   2048
#define IN_DIM 4
#define HID   256
#define G4    1024   // 4*HID

// ---------- types ----------
typedef _Float16 f16x8 __attribute__((ext_vector_type(8)));
typedef float    f32x4 __attribute__((ext_vector_type(4)));
typedef _Float16 h2_t  __attribute__((ext_vector_type(2)));

union U4H8  { uint4 u; f16x8 h; };
union U32H2 { uint32_t u; h2_t h; __half2 hh; };

__device__ __forceinline__ float fdot2(uint32_t w, uint32_t h, float acc) {
#if __has_builtin(__builtin_amdgcn_fdot2)
    U32H2 a; a.u = w; U32H2 b; b.u = h;
    return __builtin_amdgcn_fdot2(a.h, b.h, acc, false);
#else
    U32H2 a; a.u = w; U32H2 b; b.u = h;
    float2 fa = __half22float2(a.hh), fb = __half22float2(b.hh);
    return acc + fa.x * fb.x + fa.y * fb.y;
#endif
}

__device__ __forceinline__ uint32_t pack_h2(float a, float b) {
    union { uint32_t u; __half2 hh; } v;
    v.hh = __floats2half2_rn(a, b);
    return v.u;
}

__device__ __forceinline__ float sigmoidf_(float x) {
    return 1.0f / (1.0f + __expf(-x));
}
__device__ __forceinline__ float tanhf_(float x) {
    return 1.0f - 2.0f / (__expf(2.0f * x) + 1.0f);
}

// ---------- ws layout (bytes) ----------
// wfrag : 4 waves x 64 frags x 64 lanes x 16B = 262144   (rows 0..511, i/f)
// wregV : 96 planes x 512 rows x 4B          = 196608   (rows 512..1023, g/o)
// wtailV: 8 chunks x 512 rows x 16B          =  65536
#define OFF_WREGV  262144
#define OFF_WTAILV 458752
#define OFF_BIAS   524288
#define OFF_CONVF  528384
#define OFF_KSIM   529408
#define OFF_HOUT   530432

// ---------- prep ----------
// rows 0..511 (gates i,f) -> MFMA A-fragments (R3-verified packing):
//   wave w=row>>7, tile rt, chunk c, frag f=rt*8+c; lane=kblk*16+(row&15),
//   dword d packs (k even, k+1). B is packed with the same k-enumeration at
//   runtime, so the HW-internal k-order cancels.
// rows 512..1023 (gates g,o) -> R0-verified pair-col layout:
//   pair-cols [0,96) -> wregV plane pc: wregV[pc*512 + r]
//   pair-cols [96,128) -> wtailV[(c*512 + r)*4 + d]
__global__ void prep_kernel(const float* __restrict__ Whh,
                            const float* __restrict__ bih,
                            const float* __restrict__ bhh,
                            uint32_t* __restrict__ wfrag,
                            uint32_t* __restrict__ wregV,
                            uint32_t* __restrict__ wtailV,
                            float* __restrict__ bias) {
    int gid = blockIdx.x * blockDim.x + threadIdx.x;  // 0..131071
    int row = gid >> 7;      // 0..1023
    int pc  = gid & 127;     // pair-col
    float a = Whh[row * HID + 2 * pc];
    float b = Whh[row * HID + 2 * pc + 1];
    uint32_t p = pack_h2(a, b);

    if (row < 512) {
        int w    = row >> 7;
        int rr   = row & 127;
        int rt   = rr >> 4;
        int lrow = rr & 15;
        int c    = pc >> 4;
        int kk   = (2 * pc) & 31;
        int bblk = kk >> 3;
        int d    = (kk >> 1) & 3;
        int f    = rt * 8 + c;
        int lane = bblk * 16 + lrow;
        wfrag[(((w * 64 + f) * 64) + lane) * 4 + d] = p;
    } else {
        int r = row - 512;     // 0..255 = g rows, 256..511 = o rows
        if (pc < 96) {
            wregV[pc * 512 + r] = p;
        } else {
            int q = pc - 96, c = q >> 2, d = q & 3;
            wtailV[(c * 512 + r) * 4 + d] = p;
        }
    }
    if (gid < G4) bias[gid] = bih[gid] + bhh[gid];
}

// ---------- features: conv mean + RBF kernel sim ----------
__global__ void feat_kernel(const float* __restrict__ x,
                            const float* __restrict__ conv_w,
                            const float* __restrict__ conv_b,
                            float* __restrict__ convf,
                            float* __restrict__ ksim) {
    int b = blockIdx.x, t = threadIdx.x;  // 256 threads
    const float4* xb = (const float4*)(x + (size_t)b * SEQ * IN_DIM);
    float cw0 = conv_w[0], cw1 = conv_w[1], cw2 = conv_w[2], cw3 = conv_w[3];
    float cb = conv_b[0];
    float s_sig = 0.f, s_sq = 0.f;
#pragma unroll
    for (int k = 0; k < 8; ++k) {
        int s = t + k * 256;
        float4 v = xb[s];
        float d = v.x * cw0 + v.y * cw1 + v.z * cw2 + v.w * cw3 + cb;
        s_sig += sigmoidf_(d);
        s_sq  += v.x * v.x + v.y * v.y + v.z * v.z + v.w * v.w;
    }
    __shared__ float sA[256], sB[256];
    sA[t] = s_sig; sB[t] = s_sq;
    __syncthreads();
    for (int off = 128; off > 0; off >>= 1) {
        if (t < off) { sA[t] += sA[t + off]; sB[t] += sB[t + off]; }
        __syncthreads();
    }
    if (t == 0) {
        convf[b] = sA[0] * (1.0f / 2048.0f);
        ksim[b]  = __expf(-sB[0]);
    }
}

// ---------- LSTM recurrence: wave-specialized hybrid ----------
// 512 threads = 8 waves, 1 sample/block.
//  waves 0-3 (t<256): MFMA on gate rows i,f (0..511). Per wave: 8 row-tiles
//    x 8 K-chunks of v_mfma_f32_16x16x32_f16; A: 45 frags in regs/AGPR
//    (native MFMA operands, zero bounce) + 19 in LDS; B: h broadcast to 16
//    cols. Col-0 lanes write raw z to zbuf. Matrix pipe ~1242 cyc/SIMD/step.
//  waves 4-7 (t>=256): VALU dot2 on gate rows g,o (512..1023). Lane u owns
//    rows g_u,o_u: 96 pair-cols in regs + 32 in LDS; plus the ENTIRE
//    epilogue: f32 x-parts for all 4 gates, gates, thread-local c/h.
//    Issue ~700-1100 cyc/SIMD/step -> hides under the matrix pipe (m114:
//    MFMA+VALU co-schedule from different waves).
// Two separate loops (disjoint register liveness for afr[] vs wg/wo[]),
// identical barrier counts (2/step).
#define LDSF_DW  19456                  // 4 waves x 19 frags x 64 lanes x 4dw
#define TAILV_DW 16384                  // 8 x 512 x 4dw
#define ZBUF_DW  (LDSF_DW + TAILV_DW)   // 35840
#define HBUF0_DW (ZBUF_DW + 512)        // 36352
#define HBUF1_DW (HBUF0_DW + 128)       // 36480
#define SMEM_DW  (HBUF1_DW + 128)       // 36608 dw = 146432 B

__global__ __launch_bounds__(512, 2)
void recur_kernel(const float* __restrict__ x,
                  const float* __restrict__ Wih,
                  const uint4* __restrict__ wfrag,
                  const uint32_t* __restrict__ wregV,
                  const uint4* __restrict__ wtailV,
                  const float* __restrict__ bias,
                  float* __restrict__ h_out) {
    extern __shared__ uint32_t smem[];
    uint4*    ldsf  = (uint4*)smem;                  // [4][19][64] uint4
    uint4*    tailV = (uint4*)(smem + LDSF_DW);      // [8][512] uint4
    float*    zbuf  = (float*)(smem + ZBUF_DW);      // 512 f32 (zi|zf raw)
    uint32_t* hbuf0 = smem + HBUF0_DW;               // 256 fp16
    uint32_t* hbuf1 = smem + HBUF1_DW;

    const int b = blockIdx.x;
    const int t = threadIdx.x;
    const int lane = t & 63;
    const int w = t >> 6;

    // stage VALU-side weight tail (coalesced, layout identical to global)
#pragma unroll
    for (int i = 0; i < 8; ++i) tailV[t + i * 512] = wtailV[t + i * 512];
    if (t < 128) hbuf0[t] = 0u;   // h = 0

    uint32_t* hr = hbuf0;
    uint32_t* hw = hbuf1;

    if (t < 256) {
        // ================= MFMA waves (rows 0..511 = gates i,f) ==========
        uint4 afr[45];
#pragma unroll
        for (int f = 0; f < 45; ++f) afr[f] = wfrag[(w * 64 + f) * 64 + lane];
#pragma unroll
        for (int f = 0; f < 19; ++f)
            ldsf[(w * 19 + f) * 64 + lane] = wfrag[(w * 64 + 45 + f) * 64 + lane];
#pragma unroll
        for (int f = 0; f < 45; ++f) {
            asm volatile("" : "+v"(afr[f].x), "+v"(afr[f].y),
                              "+v"(afr[f].z), "+v"(afr[f].w));
        }
        const uint4* ldsw = ldsf + w * 19 * 64 + lane;
        const int boff = (lane >> 4) << 4;

        __syncthreads();

        for (int s = 0; s < SEQ; ++s) {
            f32x4 acc[8];
#pragma unroll
            for (int rt = 0; rt < 8; ++rt) acc[rt] = (f32x4){0.f, 0.f, 0.f, 0.f};

            const char* hrb = (const char*)hr;
#pragma unroll
            for (int c = 0; c < 8; ++c) {
                U4H8 hb_;
                hb_.u = *(const uint4*)(hrb + c * 64 + boff);  // broadcast
#pragma unroll
                for (int rt = 0; rt < 8; ++rt) {
                    const int f = rt * 8 + c;          // compile-time
                    U4H8 ab;
                    if (f < 45) ab.u = afr[f];
                    else        ab.u = ldsw[(f - 45) * 64];
                    acc[rt] = __builtin_amdgcn_mfma_f32_16x16x32_f16(
                        ab.h, hb_.h, acc[rt], 0, 0, 0);
                }
            }
            // raw z for rows w*128 + rt*16 + q*4 + reg (verified C/D map)
            if ((lane & 15) == 0) {
                const int q = lane >> 4;
#pragma unroll
                for (int rt = 0; rt < 8; ++rt)
                    *(f32x4*)(zbuf + w * 128 + rt * 16 + q * 4) = acc[rt];
            }
            __syncthreads();   // b1: zbuf ready for VALU waves
            __syncthreads();   // b2: epilogue done, h(s+1) ready
            uint32_t* tmp = hr; hr = hw; hw = tmp;
        }
    } else {
        // ================= VALU waves (rows 512..1023 = g,o + epilogue) ==
        const int u = t - 256;           // unit 0..255
        uint32_t wg[96], wo[96];
#pragma unroll
        for (int k = 0; k < 96; ++k) {
            wg[k] = wregV[k * 512 + u];
            wo[k] = wregV[k * 512 + 256 + u];
        }
#pragma unroll
        for (int k = 0; k < 96; ++k) {
            asm volatile("" : "+v"(wg[k]), "+v"(wo[k]));
        }
        const float4 wvi = ((const float4*)Wih)[u];
        const float4 wvf = ((const float4*)Wih)[u + 256];
        const float4 wvg = ((const float4*)Wih)[u + 512];
        const float4 wvo = ((const float4*)Wih)[u + 768];
        const float bsi = bias[u],       bsf = bias[u + 256];
        const float bsg = bias[u + 512], bso = bias[u + 768];
        const float4* xb = (const float4*)(x + (size_t)b * SEQ * IN_DIM);
        const uint4* tg = tailV + u;
        const uint4* to = tailV + 256 + u;

        float c_state = 0.f, h_last = 0.f;

        __syncthreads();

        for (int s = 0; s < SEQ; ++s) {
            const float4 xt = xb[s];
            float ag = 0.f, ag2 = 0.f, ao = 0.f, ao2 = 0.f;
            const uint4* hr4 = (const uint4*)hr;
#pragma unroll
            for (int c = 0; c < 24; ++c) {
                const uint4 h4 = hr4[c];
                ag  = fdot2(wg[4 * c + 0], h4.x, ag);
                ag2 = fdot2(wg[4 * c + 1], h4.y, ag2);
                ag  = fdot2(wg[4 * c + 2], h4.z, ag);
                ag2 = fdot2(wg[4 * c + 3], h4.w, ag2);
                ao  = fdot2(wo[4 * c + 0], h4.x, ao);
                ao2 = fdot2(wo[4 * c + 1], h4.y, ao2);
                ao  = fdot2(wo[4 * c + 2], h4.z, ao);
                ao2 = fdot2(wo[4 * c + 3], h4.w, ao2);
            }
#pragma unroll
            for (int c = 0; c < 8; ++c) {
                const uint4 wt1 = tg[c * 512];
                const uint4 wt2 = to[c * 512];
                const uint4 h4  = hr4[24 + c];
                ag  = fdot2(wt1.x, h4.x, ag);
                ag2 = fdot2(wt1.y, h4.y, ag2);
                ag  = fdot2(wt1.z, h4.z, ag);
                ag2 = fdot2(wt1.w, h4.w, ag2);
                ao  = fdot2(wt2.x, h4.x, ao);
                ao2 = fdot2(wt2.y, h4.y, ao2);
                ao  = fdot2(wt2.z, h4.z, ao);
                ao2 = fdot2(wt2.w, h4.w, ao2);
            }
            const float zg = ag + ag2 + bsg
                + xt.x * wvg.x + xt.y * wvg.y + xt.z * wvg.z + xt.w * wvg.w;
            const float zo = ao + ao2 + bso
                + xt.x * wvo.x + xt.y * wvo.y + xt.z * wvo.z + xt.w * wvo.w;
            const float gg = tanhf_(zg);
            const float og = sigmoidf_(zo);
            __syncthreads();   // b1: zbuf (raw zi,zf) ready
            const float zi = zbuf[u] + bsi
                + xt.x * wvi.x + xt.y * wvi.y + xt.z * wvi.z + xt.w * wvi.w;
            const float zf = zbuf[256 + u] + bsf
                + xt.x * wvf.x + xt.y * wvf.y + xt.z * wvf.z + xt.w * wvf.w;
            const float ig = sigmoidf_(zi);
            const float fg = sigmoidf_(zf);
            c_state = fg * c_state + ig * gg;
            h_last  = og * tanhf_(c_state);
            ((__half*)hw)[u] = __float2half_rn(h_last);
            __syncthreads();   // b2
            uint32_t* tmp = hr; hr = hw; hw = tmp;
        }
        h_out[b * HID + u] = h_last;
    }
}

// ---------- head: fc + relu + out + softmax ----------
__global__ void head_kernel(const float* __restrict__ fc_w,
                            const float* __restrict__ fc_b,
                            const float* __restrict__ out_w,
                            const float* __restrict__ out_b,
                            const float* __restrict__ convf,
                            const float* __restrict__ ksim,
                            const float* __restrict__ h_out,
                            float* __restrict__ out) {
    int b = blockIdx.x, j = threadIdx.x;  // 256 threads
    const float* hrow = h_out + b * HID;
    const float* w = fc_w + j * (HID + 2);
    float acc = fc_b[j] + w[0] * convf[b] + w[HID + 1] * ksim[b];
#pragma unroll 8
    for (int k = 0; k < HID; ++k) acc += w[1 + k] * hrow[k];
    float hid = fmaxf(acc, 0.f);
    __shared__ float r0[256], r1[256];
    r0[j] = hid * out_w[j];
    r1[j] = hid * out_w[HID + j];
    __syncthreads();
    for (int off = 128; off > 0; off >>= 1) {
        if (j < off) { r0[j] += r0[j + off]; r1[j] += r1[j + off]; }
        __syncthreads();
    }
    if (j == 0) {
        float l0 = r0[0] + out_b[0];
        float l1 = r1[0] + out_b[1];
        float m = fmaxf(l0, l1);
        float e0 = __expf(l0 - m), e1 = __expf(l1 - m);
        float inv = 1.0f / (e0 + e1);
        out[b * 2 + 0] = e0 * inv;
        out[b * 2 + 1] = e1 * inv;
    }
}

// ---------- launch ----------
extern "C" void kernel_launch(void* const* d_in, const int* in_sizes, int n_in,
                              void* d_out, int out_size, void* d_ws, size_t ws_size,
                              hipStream_t stream) {
    const float* x      = (const float*)d_in[0];
    const float* conv_w = (const float*)d_in[1];
    const float* conv_b = (const float*)d_in[2];
    const float* Wih    = (const float*)d_in[3];
    const float* Whh    = (const float*)d_in[4];
    const float* bih    = (const float*)d_in[5];
    const float* bhh    = (const float*)d_in[6];
    const float* fcw    = (const float*)d_in[7];
    const float* fcb    = (const float*)d_in[8];
    const float* outw   = (const float*)d_in[9];
    const float* outb   = (const float*)d_in[10];
    float* out = (float*)d_out;

    uint8_t* ws = (uint8_t*)d_ws;
    uint32_t* wfrag  = (uint32_t*)ws;
    uint32_t* wregV  = (uint32_t*)(ws + OFF_WREGV);
    uint32_t* wtailV = (uint32_t*)(ws + OFF_WTAILV);
    float* bias  = (float*)(ws + OFF_BIAS);
    float* convf = (float*)(ws + OFF_CONVF);
    float* ksim  = (float*)(ws + OFF_KSIM);
    float* h_out = (float*)(ws + OFF_HOUT);

    prep_kernel<<<512, 256, 0, stream>>>(Whh, bih, bhh, wfrag, wregV, wtailV, bias);
    feat_kernel<<<BATCH, 256, 0, stream>>>(x, conv_w, conv_b, convf, ksim);

    const size_t smem_bytes = (size_t)SMEM_DW * 4;  // 146432 B
    hipFuncSetAttribute((const void*)recur_kernel,
                        hipFuncAttributeMaxDynamicSharedMemorySize, (int)smem_bytes);
    recur_kernel<<<BATCH, 512, smem_bytes, stream>>>(
        x, Wih, (const uint4*)wfrag, wregV, (const uint4*)wtailV, bias, h_out);

    head_kernel<<<BATCH, 256, 0, stream>>>(fcw, fcb, outw, outb, convf, ksim, h_out, out);
}

// Round 5
// 3704.370 us; speedup vs baseline: 1.0689x; 1.0115x over previous
//
#include <hip/hip_runtime.h>
#include <hip/hip_fp16.h>
#include <cstdint>

#define BATCH 256
#define SEQ   2048
#define IN_DIM 4
#define HID   256
#define G4    1024   // 4*HID

// ---------- types ----------
typedef _Float16 f16x8 __attribute__((ext_vector_type(8)));
typedef float    f32x4 __attribute__((ext_vector_type(4)));

union U4H8 { uint4 u; f16x8 h; };

__device__ __forceinline__ uint32_t pack_h2(float a, float b) {
    union { uint32_t u; __half2 hh; } v;
    v.hh = __floats2half2_rn(a, b);   // a -> lo (k even), b -> hi (k odd)
    return v.u;
}

__device__ __forceinline__ float sigmoidf_(float x) {
    return 1.0f / (1.0f + __expf(-x));
}
__device__ __forceinline__ float tanhf_(float x) {
    return 1.0f - 2.0f / (__expf(2.0f * x) + 1.0f);
}

// ---------- ws layout (bytes) ----------
// wfrag: 8 waves x 64 frags x 64 lanes x 16B = 524288
#define OFF_BIAS  524288
#define OFF_CONVF 528384
#define OFF_KSIM  529408
#define OFF_HOUT  530432

// ---------- prep: build TRANSPOSED MFMA B-fragments (Whh^T) ----------
// z = Whh*h computed as D = A(h bcast rows) x B(Whh^T).  B[k][c] =
// Whh[gate-row][k] where the gate-row -> (wave w, tile tt, col c) map is:
//   g = row>>8 (gate), rem = row&255, w = rem>>5, s = (rem>>4)&1, c = row&15
//   tt = g*2+s  (tiles 0,1=i  2,3=f  4,5=g  6,7=o), frag f = tt*8 + kc
// k-enumeration (same convention both operands; symmetry verified by R3's
// bit-exact pass): lane = kblk*16 + c, dword d packs (k even, k odd) with
// kc = pc>>4, kblk = (pc>>2)&3, d = pc&3.
// Every lane's D col (lane&15) = z of a unit this lane's epilogue owns.
__global__ void prep_kernel(const float* __restrict__ Whh,
                            const float* __restrict__ bih,
                            const float* __restrict__ bhh,
                            uint32_t* __restrict__ wfrag,
                            float* __restrict__ bias) {
    int gid = blockIdx.x * blockDim.x + threadIdx.x;  // 0..131071
    int row = gid >> 7;      // gate-row 0..1023
    int pc  = gid & 127;     // pair-col (k0 = 2*pc)
    float a = Whh[row * HID + 2 * pc];
    float b = Whh[row * HID + 2 * pc + 1];
    uint32_t p = pack_h2(a, b);

    int g    = row >> 8;
    int rem  = row & 255;
    int w    = rem >> 5;
    int s    = (rem >> 4) & 1;
    int c    = row & 15;
    int tt   = g * 2 + s;
    int kc   = pc >> 4;
    int kblk = (pc >> 2) & 3;
    int d    = pc & 3;
    int f    = tt * 8 + kc;
    int lane = kblk * 16 + c;
    wfrag[(((w * 64 + f) * 64) + lane) * 4 + d] = p;

    if (gid < G4) bias[gid] = bih[gid] + bhh[gid];
}

// ---------- features: conv mean + RBF kernel sim ----------
__global__ void feat_kernel(const float* __restrict__ x,
                            const float* __restrict__ conv_w,
                            const float* __restrict__ conv_b,
                            float* __restrict__ convf,
                            float* __restrict__ ksim) {
    int b = blockIdx.x, t = threadIdx.x;  // 256 threads
    const float4* xb = (const float4*)(x + (size_t)b * SEQ * IN_DIM);
    float cw0 = conv_w[0], cw1 = conv_w[1], cw2 = conv_w[2], cw3 = conv_w[3];
    float cb = conv_b[0];
    float s_sig = 0.f, s_sq = 0.f;
#pragma unroll
    for (int k = 0; k < 8; ++k) {
        int s = t + k * 256;
        float4 v = xb[s];
        float d = v.x * cw0 + v.y * cw1 + v.z * cw2 + v.w * cw3 + cb;
        s_sig += sigmoidf_(d);
        s_sq  += v.x * v.x + v.y * v.y + v.z * v.z + v.w * v.w;
    }
    __shared__ float sA[256], sB[256];
    sA[t] = s_sig; sB[t] = s_sq;
    __syncthreads();
    for (int off = 128; off > 0; off >>= 1) {
        if (t < off) { sA[t] += sA[t + off]; sB[t] += sB[t + off]; }
        __syncthreads();
    }
    if (t == 0) {
        convf[b] = sA[0] * (1.0f / 2048.0f);
        ksim[b]  = __expf(-sB[0]);
    }
}

// ---------- LSTM recurrence: transpose-MFMA, 1 barrier/step ----------
// 512 threads = 8 waves, 1 sample/block. Wave w owns units [w*32,(w+1)*32).
// Per step:
//   MFMA: 8 k-chunks x 8 tiles, A = h broadcast (b128 from LDS, kblk-slice),
//     B = Whh^T frags: 45 register-resident ("+v" pinned, AGPR-native) + 19
//     from LDS. Odd waves run tiles 7..0 (LDS frags first), even waves 0..7
//     -> anti-phased LDS/MFMA across the 2 waves per SIMD.
//   Epilogue (in-lane, no z exchange!): lane (w, c=lane&15) holds z of units
//     uA=w*32+c, uB=uA+16 for all 4 gates in acc[0..7][0]; adds the
//     precomputed xz = Wih*x_t + bias (f16 LDS, pipelined), gates, c/h local.
//   Pipeline: xz(s+1) computed during step s (2 rows/thread, Wih rows in
//     regs); h(s+1) written by lanes<16. ONE __syncthreads per step.
#define LDSF_U4 (8 * 19 * 64)          // 9728 uint4 (152KB)
#define LDSF_DW (LDSF_U4 * 4)          // 38912
#define HB0_DW  (LDSF_DW)              // 128 dw (256 fp16)
#define HB1_DW  (HB0_DW + 128)
#define XZ0_DW  (HB1_DW + 128)         // 512 dw (1024 fp16)
#define XZ1_DW  (XZ0_DW + 512)
#define SMEM_DW (XZ1_DW + 512)         // 40192 dw = 160768 B

__global__ __launch_bounds__(512, 2)
void recur_kernel(const float* __restrict__ x,
                  const float* __restrict__ Wih,
                  const uint4* __restrict__ wfrag,
                  const float* __restrict__ bias,
                  float* __restrict__ h_out) {
    extern __shared__ uint32_t smem[];
    uint4*  ldsf = (uint4*)smem;               // [8][19][64] uint4
    uint32_t* hb0 = smem + HB0_DW;
    uint32_t* hb1 = smem + HB1_DW;
    __half* xz0 = (__half*)(smem + XZ0_DW);
    __half* xz1 = (__half*)(smem + XZ1_DW);

    const int b = blockIdx.x;
    const int t = threadIdx.x;
    const int lane = t & 63;
    const int w = t >> 6;
    const int cl = lane & 15;
    const int uA = w * 32 + cl;
    const int uB = uA + 16;

    // B-fragments: 45 register-resident + 19 staged to LDS
    uint4 rfrag[45];
#pragma unroll
    for (int f = 0; f < 45; ++f) rfrag[f] = wfrag[(w * 64 + f) * 64 + lane];
#pragma unroll
    for (int j = 0; j < 19; ++j)
        ldsf[(w * 19 + j) * 64 + lane] = wfrag[(w * 64 + 45 + j) * 64 + lane];
    if (t < 128) hb0[t] = 0u;   // h = 0
#pragma unroll
    for (int f = 0; f < 45; ++f) {
        asm volatile("" : "+v"(rfrag[f].x), "+v"(rfrag[f].y),
                          "+v"(rfrag[f].z), "+v"(rfrag[f].w));
    }

    // xz pipeline: this thread owns gate-rows t and t+512
    const int r1 = t, r2 = t + 512;
    const float4 wr1 = ((const float4*)Wih)[r1];
    const float4 wr2 = ((const float4*)Wih)[r2];
    const float bs1 = bias[r1], bs2 = bias[r2];
    const float4* xb = (const float4*)(x + (size_t)b * SEQ * IN_DIM);

    {   // xz(0)
        const float4 x0 = xb[0];
        xz0[r1] = __float2half_rn(bs1 + x0.x*wr1.x + x0.y*wr1.y + x0.z*wr1.z + x0.w*wr1.w);
        xz0[r2] = __float2half_rn(bs2 + x0.x*wr2.x + x0.y*wr2.y + x0.z*wr2.z + x0.w*wr2.w);
    }

    const uint4* lbase = ldsf + (w * 19) * 64 + lane;
    const int boff = (lane >> 4) << 4;   // kblk byte offset into h chunk

    float cA = 0.f, cB = 0.f, hA = 0.f, hB = 0.f;

    __syncthreads();

    uint32_t* hr = hb0; uint32_t* hw = hb1;
    __half* xzr = xz0; __half* xzw = xz1;

    for (int s = 0; s < SEQ; ++s) {
        f32x4 acc[8];
#pragma unroll
        for (int i = 0; i < 8; ++i) acc[i] = (f32x4){0.f, 0.f, 0.f, 0.f};

        const char* hrb = (const char*)hr;
        if (w & 1) {   // odd waves: LDS-resident tiles first
#pragma unroll
            for (int kc = 0; kc < 8; ++kc) {
                U4H8 hk; hk.u = *(const uint4*)(hrb + kc * 64 + boff);
#pragma unroll
                for (int ttd = 0; ttd < 8; ++ttd) {
                    const int tt = 7 - ttd;
                    const int f = tt * 8 + kc;   // compile-time
                    U4H8 bb;
                    if (f < 45) bb.u = rfrag[f];
                    else        bb.u = lbase[(f - 45) * 64];
                    acc[tt] = __builtin_amdgcn_mfma_f32_16x16x32_f16(
                        hk.h, bb.h, acc[tt], 0, 0, 0);
                }
            }
        } else {       // even waves: register tiles first
#pragma unroll
            for (int kc = 0; kc < 8; ++kc) {
                U4H8 hk; hk.u = *(const uint4*)(hrb + kc * 64 + boff);
#pragma unroll
                for (int tt = 0; tt < 8; ++tt) {
                    const int f = tt * 8 + kc;   // compile-time
                    U4H8 bb;
                    if (f < 45) bb.u = rfrag[f];
                    else        bb.u = lbase[(f - 45) * 64];
                    acc[tt] = __builtin_amdgcn_mfma_f32_16x16x32_f16(
                        hk.h, bb.h, acc[tt], 0, 0, 0);
                }
            }
        }

        // in-lane epilogue: all 4 gates of units uA,uB live in acc[*][0]
        const float ziA = acc[0][0] + __half2float(xzr[uA]);
        const float ziB = acc[1][0] + __half2float(xzr[uB]);
        const float zfA = acc[2][0] + __half2float(xzr[256 + uA]);
        const float zfB = acc[3][0] + __half2float(xzr[256 + uB]);
        const float zgA = acc[4][0] + __half2float(xzr[512 + uA]);
        const float zgB = acc[5][0] + __half2float(xzr[512 + uB]);
        const float zoA = acc[6][0] + __half2float(xzr[768 + uA]);
        const float zoB = acc[7][0] + __half2float(xzr[768 + uB]);
        cA = sigmoidf_(zfA) * cA + sigmoidf_(ziA) * tanhf_(zgA);
        hA = sigmoidf_(zoA) * tanhf_(cA);
        cB = sigmoidf_(zfB) * cB + sigmoidf_(ziB) * tanhf_(zgB);
        hB = sigmoidf_(zoB) * tanhf_(cB);

        // xz(s+1): overlapped with other waves' MFMA/epilogue
        {
            const int sn = (s + 1 < SEQ) ? s + 1 : SEQ - 1;
            const float4 xn = xb[sn];
            xzw[r1] = __float2half_rn(bs1 + xn.x*wr1.x + xn.y*wr1.y + xn.z*wr1.z + xn.w*wr1.w);
            xzw[r2] = __float2half_rn(bs2 + xn.x*wr2.x + xn.y*wr2.y + xn.z*wr2.z + xn.w*wr2.w);
        }
        // h(s+1): one row-group copy writes
        if (lane < 16) {
            ((__half*)hw)[uA] = __float2half_rn(hA);
            ((__half*)hw)[uB] = __float2half_rn(hB);
        }
        __syncthreads();   // the ONLY barrier per step
        { uint32_t* tp = hr; hr = hw; hw = tp; }
        { __half* tp = xzr; xzr = xzw; xzw = tp; }
    }

    if (lane < 16) {
        h_out[b * HID + uA] = hA;
        h_out[b * HID + uB] = hB;
    }
}

// ---------- head: fc + relu + out + softmax ----------
__global__ void head_kernel(const float* __restrict__ fc_w,
                            const float* __restrict__ fc_b,
                            const float* __restrict__ out_w,
                            const float* __restrict__ out_b,
                            const float* __restrict__ convf,
                            const float* __restrict__ ksim,
                            const float* __restrict__ h_out,
                            float* __restrict__ out) {
    int b = blockIdx.x, j = threadIdx.x;  // 256 threads
    const float* hrow = h_out + b * HID;
    const float* w = fc_w + j * (HID + 2);
    float acc = fc_b[j] + w[0] * convf[b] + w[HID + 1] * ksim[b];
#pragma unroll 8
    for (int k = 0; k < HID; ++k) acc += w[1 + k] * hrow[k];
    float hid = fmaxf(acc, 0.f);
    __shared__ float r0[256], r1[256];
    r0[j] = hid * out_w[j];
    r1[j] = hid * out_w[HID + j];
    __syncthreads();
    for (int off = 128; off > 0; off >>= 1) {
        if (j < off) { r0[j] += r0[j + off]; r1[j] += r1[j + off]; }
        __syncthreads();
    }
    if (j == 0) {
        float l0 = r0[0] + out_b[0];
        float l1 = r1[0] + out_b[1];
        float m = fmaxf(l0, l1);
        float e0 = __expf(l0 - m), e1 = __expf(l1 - m);
        float inv = 1.0f / (e0 + e1);
        out[b * 2 + 0] = e0 * inv;
        out[b * 2 + 1] = e1 * inv;
    }
}

// ---------- launch ----------
extern "C" void kernel_launch(void* const* d_in, const int* in_sizes, int n_in,
                              void* d_out, int out_size, void* d_ws, size_t ws_size,
                              hipStream_t stream) {
    const float* x      = (const float*)d_in[0];
    const float* conv_w = (const float*)d_in[1];
    const float* conv_b = (const float*)d_in[2];
    const float* Wih    = (const float*)d_in[3];
    const float* Whh    = (const float*)d_in[4];
    const float* bih    = (const float*)d_in[5];
    const float* bhh    = (const float*)d_in[6];
    const float* fcw    = (const float*)d_in[7];
    const float* fcb    = (const float*)d_in[8];
    const float* outw   = (const float*)d_in[9];
    const float* outb   = (const float*)d_in[10];
    float* out = (float*)d_out;

    uint8_t* ws = (uint8_t*)d_ws;
    uint32_t* wfrag = (uint32_t*)ws;
    float* bias  = (float*)(ws + OFF_BIAS);
    float* convf = (float*)(ws + OFF_CONVF);
    float* ksim  = (float*)(ws + OFF_KSIM);
    float* h_out = (float*)(ws + OFF_HOUT);

    prep_kernel<<<512, 256, 0, stream>>>(Whh, bih, bhh, wfrag, bias);
    feat_kernel<<<BATCH, 256, 0, stream>>>(x, conv_w, conv_b, convf, ksim);

    const size_t smem_bytes = (size_t)SMEM_DW * 4;  // 160768 B
    hipFuncSetAttribute((const void*)recur_kernel,
                        hipFuncAttributeMaxDynamicSharedMemorySize, (int)smem_bytes);
    recur_kernel<<<BATCH, 512, smem_bytes, stream>>>(
        x, Wih, (const uint4*)wfrag, bias, h_out);

    head_kernel<<<BATCH, 256, 0, stream>>>(fcw, fcb, outw, outb, convf, ksim, h_out, out);
}

// Round 6
// 2514.477 us; speedup vs baseline: 1.5747x; 1.4732x over previous
//
#include <hip/hip_runtime.h>
#include <hip/hip_fp16.h>
#include <cstdint>

#define BATCH 256
#define SEQ   2048
#define IN_DIM 4
#define HID   256
#define G4    1024   // 4*HID

// ---------- types ----------
typedef int   i32x8 __attribute__((ext_vector_type(8)));
typedef float f32x4 __attribute__((ext_vector_type(4)));

union U328 { i32x8 v; uint4 q[2]; };

__device__ __forceinline__ float sigmoidf_(float x) {
    return 1.0f / (1.0f + __expf(-x));
}
__device__ __forceinline__ float tanhf_(float x) {
    return 1.0f - 2.0f / (__expf(2.0f * x) + 1.0f);
}

// OCP e4m3fn encode (RNE). |a| <= 1 assumed (weights pre-scaled, h bounded).
__device__ __forceinline__ uint32_t enc_e4m3_sw(float a) {
    uint32_t bits = __float_as_uint(a);
    uint32_t s = (bits >> 24) & 0x80u;
    float am = __uint_as_float(bits & 0x7FFFFFFFu);
    if (am < 0.015625f) {                       // < 2^-6: denormal grid 2^-9
        uint32_t d = (uint32_t)__float2int_rn(am * 512.0f);  // 0..8
        return s | d;                           // d==8 -> 0x08 == 2^-6 exactly
    }
    uint32_t mag = bits & 0x7FFFFFFFu;
    uint32_t lsb = (mag >> 20) & 1u;
    uint32_t r = mag + 0x0007FFFFu + lsb;       // RNE at mantissa bit 20
    int E = (int)(r >> 23) - 127 + 7;
    uint32_t m3 = (r >> 20) & 7u;
    if (E > 15) { E = 15; m3 = 6u; }            // clamp to 448
    return s | ((uint32_t)E << 3) | m3;
}

__device__ __forceinline__ uint32_t enc_e4m3(float a) {
#if __has_builtin(__builtin_amdgcn_cvt_pk_fp8_f32)
    return (uint32_t)__builtin_amdgcn_cvt_pk_fp8_f32(a, a, 0, false) & 0xFFu;
#else
    return enc_e4m3_sw(a);
#endif
}

__device__ __forceinline__ uint32_t pack4_e4m3(float v0, float v1, float v2, float v3) {
#if __has_builtin(__builtin_amdgcn_cvt_pk_fp8_f32)
    int r = __builtin_amdgcn_cvt_pk_fp8_f32(v0, v1, 0, false);
    r = __builtin_amdgcn_cvt_pk_fp8_f32(v2, v3, r, true);
    return (uint32_t)r;
#else
    return enc_e4m3_sw(v0) | (enc_e4m3_sw(v1) << 8) |
           (enc_e4m3_sw(v2) << 16) | (enc_e4m3_sw(v3) << 24);
#endif
}

// ---------- ws layout (bytes) ----------
// wfragP: 8 waves x 16 frags x 64 lanes x 32B = 262144 (all weights, fp8)
#define OFF_BIAS  262144
#define OFF_CONVF 266240
#define OFF_KSIM  267264
#define OFF_HOUT  268288

// e8m0 scales: uniform -> byte-select / operand-order provably irrelevant
#define SCALE_H 0x7F7F7F7Fu   // 2^0
#define SCALE_W 0x7B7B7B7Bu   // 2^-4 (weights pre-scaled x16 -> avoids denormals)

// ---------- prep: build fp8 MX B-fragments (Whh^T x16) + fused bias ----------
// z = Whh*h as D = A(h bcast rows) x B(Whh^T), mfma_scale_f32_16x16x128_f8f6f4.
// Unit->tile map (identical to R5, verified): wave w owns units [w*32,(w+1)*32);
//   tt = g*2+s (g gate, s sub), col c: unit u = w*32 + s*16 + c, row = g*256+u.
// k-enum (same for A and B -> HW-internal k-order cancels, R3-proven):
//   lane = kb*16 + c, byte j in lane's 32B slice: k = kc*128 + kb*32 + j.
// frag f = tt*2 + kc (16 frags/wave, v8i32 each).
// One thread per dword: gid -> d(0..7), lane, f, w.
__global__ void prep_kernel(const float* __restrict__ Whh,
                            const float* __restrict__ bih,
                            const float* __restrict__ bhh,
                            uint32_t* __restrict__ wfragP,
                            float* __restrict__ bias) {
    int gid = blockIdx.x * blockDim.x + threadIdx.x;  // 0..65535
    int d    = gid & 7;
    int lane = (gid >> 3) & 63;
    int f    = (gid >> 9) & 15;
    int w    = gid >> 13;
    int c  = lane & 15;
    int kb = lane >> 4;
    int tt = f >> 1;
    int kc = f & 1;
    int g  = tt >> 1;
    int s  = tt & 1;
    int u   = w * 32 + s * 16 + c;
    int row = g * 256 + u;
    int k0  = kc * 128 + kb * 32 + d * 4;
    const float* src = Whh + (size_t)row * HID + k0;
    uint32_t p = pack4_e4m3(src[0] * 16.0f, src[1] * 16.0f,
                            src[2] * 16.0f, src[3] * 16.0f);
    wfragP[(size_t)gid] = p;   // gid == ((w*16+f)*64+lane)*8 + d by construction

    if (gid < G4) bias[gid] = bih[gid] + bhh[gid];
}

// ---------- features: conv mean + RBF kernel sim ----------
__global__ void feat_kernel(const float* __restrict__ x,
                            const float* __restrict__ conv_w,
                            const float* __restrict__ conv_b,
                            float* __restrict__ convf,
                            float* __restrict__ ksim) {
    int b = blockIdx.x, t = threadIdx.x;  // 256 threads
    const float4* xb = (const float4*)(x + (size_t)b * SEQ * IN_DIM);
    float cw0 = conv_w[0], cw1 = conv_w[1], cw2 = conv_w[2], cw3 = conv_w[3];
    float cb = conv_b[0];
    float s_sig = 0.f, s_sq = 0.f;
#pragma unroll
    for (int k = 0; k < 8; ++k) {
        int s = t + k * 256;
        float4 v = xb[s];
        float d = v.x * cw0 + v.y * cw1 + v.z * cw2 + v.w * cw3 + cb;
        s_sig += sigmoidf_(d);
        s_sq  += v.x * v.x + v.y * v.y + v.z * v.z + v.w * v.w;
    }
    __shared__ float sA[256], sB[256];
    sA[t] = s_sig; sB[t] = s_sq;
    __syncthreads();
    for (int off = 128; off > 0; off >>= 1) {
        if (t < off) { sA[t] += sA[t + off]; sB[t] += sB[t + off]; }
        __syncthreads();
    }
    if (t == 0) {
        convf[b] = sA[0] * (1.0f / 2048.0f);
        ksim[b]  = __expf(-sB[0]);
    }
}

// ---------- LSTM recurrence: MX-fp8 K=128 MFMA, all weights in VGPRs ----------
// 512 threads = 8 waves, 1 sample/block. Per step per wave: 16 x
// mfma_scale_f32_16x16x128_f8f6f4 (8 tiles x 2 k-chunks) -> matrix-pipe floor
// ~1107 cyc/SIMD (vs 2483 for the R5 f16 path). Weights: 16 v8i32 frags =
// 128 VGPRs, register-resident -> NO per-step LDS/global weight reads.
// A operand: h as fp8 in LDS (256B), lane reads its 32B k-slice (2x b128,
// broadcast within 16-lane groups). D col = lane&15 = unit -> in-lane
// epilogue identical to R5 (verified): acc[tt][0] = z, + xz(f16, pipelined),
// gates, thread-local c/h. ONE barrier per step.
#define HB0_DW  0
#define HB1_DW  64
#define XZ0_DW  128
#define XZ1_DW  640
#define SMEM_DW 1152   // 4608 B

__global__ __launch_bounds__(512, 2)
void recur_kernel(const float* __restrict__ x,
                  const float* __restrict__ Wih,
                  const uint32_t* __restrict__ wfragP,
                  const float* __restrict__ bias,
                  float* __restrict__ h_out) {
    extern __shared__ uint32_t smem[];
    uint32_t* hb0 = smem + HB0_DW;            // 256 fp8 bytes
    uint32_t* hb1 = smem + HB1_DW;
    __half* xz0 = (__half*)(smem + XZ0_DW);   // 1024 f16
    __half* xz1 = (__half*)(smem + XZ1_DW);

    const int b = blockIdx.x;
    const int t = threadIdx.x;
    const int lane = t & 63;
    const int w = t >> 6;
    const int cl = lane & 15;
    const int grp = lane >> 4;
    const int uA = w * 32 + cl;
    const int uB = uA + 16;

    // all 16 weight fragments -> registers (128 VGPRs)
    U328 rf[16];
    {
        const uint32_t* base = wfragP + (size_t)w * 8192 + (size_t)lane * 8;
#pragma unroll
        for (int f = 0; f < 16; ++f) {
            rf[f].q[0] = *(const uint4*)(base + f * 512);
            rf[f].q[1] = *(const uint4*)(base + f * 512 + 4);
        }
    }
#pragma unroll
    for (int f = 0; f < 16; ++f) asm volatile("" : "+v"(rf[f].v));

    if (t < 64) hb0[t] = 0u;   // h = 0 (fp8 zeros)

    // xz pipeline: this thread owns gate-rows t and t+512
    const int r1 = t, r2 = t + 512;
    const float4 wr1 = ((const float4*)Wih)[r1];
    const float4 wr2 = ((const float4*)Wih)[r2];
    const float bs1 = bias[r1], bs2 = bias[r2];
    const float4* xb = (const float4*)(x + (size_t)b * SEQ * IN_DIM);

    {   // xz(0)
        const float4 x0 = xb[0];
        xz0[r1] = __float2half_rn(bs1 + x0.x*wr1.x + x0.y*wr1.y + x0.z*wr1.z + x0.w*wr1.w);
        xz0[r2] = __float2half_rn(bs2 + x0.x*wr2.x + x0.y*wr2.y + x0.z*wr2.z + x0.w*wr2.w);
    }

    float cA = 0.f, cB = 0.f, hA = 0.f, hB = 0.f;

    __syncthreads();

    uint32_t* hr = hb0; uint32_t* hw = hb1;
    __half* xzr = xz0; __half* xzw = xz1;

    for (int s = 0; s < SEQ; ++s) {
        const unsigned char* hrb = (const unsigned char*)hr;
        U328 hk0, hk1;
        hk0.q[0] = *(const uint4*)(hrb + grp * 32);
        hk0.q[1] = *(const uint4*)(hrb + grp * 32 + 16);
        hk1.q[0] = *(const uint4*)(hrb + 128 + grp * 32);
        hk1.q[1] = *(const uint4*)(hrb + 128 + grp * 32 + 16);

        f32x4 acc[8];
#pragma unroll
        for (int i = 0; i < 8; ++i) acc[i] = (f32x4){0.f, 0.f, 0.f, 0.f};
#pragma unroll
        for (int tt = 0; tt < 8; ++tt) {
            acc[tt] = __builtin_amdgcn_mfma_scale_f32_16x16x128_f8f6f4(
                hk0.v, rf[2 * tt].v, acc[tt], 0, 0, 0, SCALE_H, 0, SCALE_W);
        }
#pragma unroll
        for (int tt = 0; tt < 8; ++tt) {
            acc[tt] = __builtin_amdgcn_mfma_scale_f32_16x16x128_f8f6f4(
                hk1.v, rf[2 * tt + 1].v, acc[tt], 0, 0, 0, SCALE_H, 0, SCALE_W);
        }

        // in-lane epilogue: all 4 gates of units uA,uB in acc[*][0]
        const float ziA = acc[0][0] + __half2float(xzr[uA]);
        const float ziB = acc[1][0] + __half2float(xzr[uB]);
        const float zfA = acc[2][0] + __half2float(xzr[256 + uA]);
        const float zfB = acc[3][0] + __half2float(xzr[256 + uB]);
        const float zgA = acc[4][0] + __half2float(xzr[512 + uA]);
        const float zgB = acc[5][0] + __half2float(xzr[512 + uB]);
        const float zoA = acc[6][0] + __half2float(xzr[768 + uA]);
        const float zoB = acc[7][0] + __half2float(xzr[768 + uB]);
        cA = sigmoidf_(zfA) * cA + sigmoidf_(ziA) * tanhf_(zgA);
        hA = sigmoidf_(zoA) * tanhf_(cA);
        cB = sigmoidf_(zfB) * cB + sigmoidf_(ziB) * tanhf_(zgB);
        hB = sigmoidf_(zoB) * tanhf_(cB);

        // xz(s+1): overlaps other waves' MFMA/epilogue
        {
            const int sn = (s + 1 < SEQ) ? s + 1 : SEQ - 1;
            const float4 xn = xb[sn];
            xzw[r1] = __float2half_rn(bs1 + xn.x*wr1.x + xn.y*wr1.y + xn.z*wr1.z + xn.w*wr1.w);
            xzw[r2] = __float2half_rn(bs2 + xn.x*wr2.x + xn.y*wr2.y + xn.z*wr2.z + xn.w*wr2.w);
        }
        // h(s+1) as fp8: one row-group copy writes
        if (lane < 16) {
            ((unsigned char*)hw)[uA] = (unsigned char)enc_e4m3(hA);
            ((unsigned char*)hw)[uB] = (unsigned char)enc_e4m3(hB);
        }
        __syncthreads();   // the ONLY barrier per step
        { uint32_t* tp = hr; hr = hw; hw = tp; }
        { __half* tp = xzr; xzr = xzw; xzw = tp; }
    }

    if (lane < 16) {
        h_out[b * HID + uA] = hA;
        h_out[b * HID + uB] = hB;
    }
}

// ---------- head: fc + relu + out + softmax ----------
__global__ void head_kernel(const float* __restrict__ fc_w,
                            const float* __restrict__ fc_b,
                            const float* __restrict__ out_w,
                            const float* __restrict__ out_b,
                            const float* __restrict__ convf,
                            const float* __restrict__ ksim,
                            const float* __restrict__ h_out,
                            float* __restrict__ out) {
    int b = blockIdx.x, j = threadIdx.x;  // 256 threads
    const float* hrow = h_out + b * HID;
    const float* w = fc_w + j * (HID + 2);
    float acc = fc_b[j] + w[0] * convf[b] + w[HID + 1] * ksim[b];
#pragma unroll 8
    for (int k = 0; k < HID; ++k) acc += w[1 + k] * hrow[k];
    float hid = fmaxf(acc, 0.f);
    __shared__ float r0[256], r1[256];
    r0[j] = hid * out_w[j];
    r1[j] = hid * out_w[HID + j];
    __syncthreads();
    for (int off = 128; off > 0; off >>= 1) {
        if (j < off) { r0[j] += r0[j + off]; r1[j] += r1[j + off]; }
        __syncthreads();
    }
    if (j == 0) {
        float l0 = r0[0] + out_b[0];
        float l1 = r1[0] + out_b[1];
        float m = fmaxf(l0, l1);
        float e0 = __expf(l0 - m), e1 = __expf(l1 - m);
        float inv = 1.0f / (e0 + e1);
        out[b * 2 + 0] = e0 * inv;
        out[b * 2 + 1] = e1 * inv;
    }
}

// ---------- launch ----------
extern "C" void kernel_launch(void* const* d_in, const int* in_sizes, int n_in,
                              void* d_out, int out_size, void* d_ws, size_t ws_size,
                              hipStream_t stream) {
    const float* x      = (const float*)d_in[0];
    const float* conv_w = (const float*)d_in[1];
    const float* conv_b = (const float*)d_in[2];
    const float* Wih    = (const float*)d_in[3];
    const float* Whh    = (const float*)d_in[4];
    const float* bih    = (const float*)d_in[5];
    const float* bhh    = (const float*)d_in[6];
    const float* fcw    = (const float*)d_in[7];
    const float* fcb    = (const float*)d_in[8];
    const float* outw   = (const float*)d_in[9];
    const float* outb   = (const float*)d_in[10];
    float* out = (float*)d_out;

    uint8_t* ws = (uint8_t*)d_ws;
    uint32_t* wfragP = (uint32_t*)ws;
    float* bias  = (float*)(ws + OFF_BIAS);
    float* convf = (float*)(ws + OFF_CONVF);
    float* ksim  = (float*)(ws + OFF_KSIM);
    float* h_out = (float*)(ws + OFF_HOUT);

    prep_kernel<<<256, 256, 0, stream>>>(Whh, bih, bhh, wfragP, bias);
    feat_kernel<<<BATCH, 256, 0, stream>>>(x, conv_w, conv_b, convf, ksim);

    const size_t smem_bytes = (size_t)SMEM_DW * 4;  // 4608 B
    recur_kernel<<<BATCH, 512, smem_bytes, stream>>>(x, Wih, wfragP, bias, h_out);

    head_kernel<<<BATCH, 256, 0, stream>>>(fcw, fcb, outw, outb, convf, ksim, h_out, out);
}

// Round 7
// 2298.608 us; speedup vs baseline: 1.7226x; 1.0939x over previous
//
#include <hip/hip_runtime.h>
#include <hip/hip_fp16.h>
#include <cstdint>

#define BATCH 256
#define SEQ   2048
#define IN_DIM 4
#define HID   256
#define G4    1024   // 4*HID

// ---------- types ----------
typedef int   i32x8 __attribute__((ext_vector_type(8)));
typedef float f32x4 __attribute__((ext_vector_type(4)));

union U328 { i32x8 v; uint4 q[2]; };

__device__ __forceinline__ float sigmoidf_(float x) {
    return 1.0f / (1.0f + __expf(-x));
}
__device__ __forceinline__ float tanhf_(float x) {
    return 1.0f - 2.0f / (__expf(2.0f * x) + 1.0f);
}

// OCP e4m3fn encode (RNE). |a| <= 1 assumed (weights pre-scaled, h bounded).
__device__ __forceinline__ uint32_t enc_e4m3_sw(float a) {
    uint32_t bits = __float_as_uint(a);
    uint32_t s = (bits >> 24) & 0x80u;
    float am = __uint_as_float(bits & 0x7FFFFFFFu);
    if (am < 0.015625f) {                       // < 2^-6: denormal grid 2^-9
        uint32_t d = (uint32_t)__float2int_rn(am * 512.0f);  // 0..8
        return s | d;                           // d==8 -> 0x08 == 2^-6 exactly
    }
    uint32_t mag = bits & 0x7FFFFFFFu;
    uint32_t lsb = (mag >> 20) & 1u;
    uint32_t r = mag + 0x0007FFFFu + lsb;       // RNE at mantissa bit 20
    int E = (int)(r >> 23) - 127 + 7;
    uint32_t m3 = (r >> 20) & 7u;
    if (E > 15) { E = 15; m3 = 6u; }            // clamp to 448
    return s | ((uint32_t)E << 3) | m3;
}

__device__ __forceinline__ uint32_t enc_e4m3(float a) {
#if __has_builtin(__builtin_amdgcn_cvt_pk_fp8_f32)
    return (uint32_t)__builtin_amdgcn_cvt_pk_fp8_f32(a, a, 0, false) & 0xFFu;
#else
    return enc_e4m3_sw(a);
#endif
}

__device__ __forceinline__ uint32_t pack4_e4m3(float v0, float v1, float v2, float v3) {
#if __has_builtin(__builtin_amdgcn_cvt_pk_fp8_f32)
    int r = __builtin_amdgcn_cvt_pk_fp8_f32(v0, v1, 0, false);
    r = __builtin_amdgcn_cvt_pk_fp8_f32(v2, v3, r, true);
    return (uint32_t)r;
#else
    return enc_e4m3_sw(v0) | (enc_e4m3_sw(v1) << 8) |
           (enc_e4m3_sw(v2) << 16) | (enc_e4m3_sw(v3) << 24);
#endif
}

// ---------- ws layout (bytes) ----------
// wfragP: 16 waves x 8 frags x 64 lanes x 32B = 262144 (all weights, fp8)
#define OFF_BIAS  262144
#define OFF_CONVF 266240
#define OFF_KSIM  267264
#define OFF_HOUT  268288

// e8m0 scales: uniform -> byte-select / operand-order provably irrelevant
#define SCALE_H 0x7F7F7F7Fu   // 2^0
#define SCALE_W 0x7B7B7B7Bu   // 2^-4 (weights pre-scaled x16 -> avoids denormals)

// ---------- prep: build fp8 MX B-fragments (Whh^T x16) + fused bias ----------
// 16-wave decomposition: wave w owns units [w*16,(w+1)*16), i.e. gate-rows
// row = g*256 + w*16 + c for g=0..3 (i,f,g,o), col c = 0..15.
// 4 tiles/wave (one per gate) x 2 k-chunks -> frag f = g*2 + kc, 8 frags.
// k-enum (same for A and B -> HW-internal k-order cancels, R3/R6-proven):
//   lane = kb*16 + c; lane's 32B slice covers k = kc*128 + kb*32 + [0,32).
// One thread per dword: gid -> d(0..7), lane(6b), f(3b), w(4b);
//   gid == ((w*8+f)*64+lane)*8 + d by construction.
__global__ void prep_kernel(const float* __restrict__ Whh,
                            const float* __restrict__ bih,
                            const float* __restrict__ bhh,
                            uint32_t* __restrict__ wfragP,
                            float* __restrict__ bias) {
    int gid = blockIdx.x * blockDim.x + threadIdx.x;  // 0..65535
    int d    = gid & 7;
    int lane = (gid >> 3) & 63;
    int f    = (gid >> 9) & 7;
    int w    = gid >> 12;
    int c  = lane & 15;
    int kb = lane >> 4;
    int g  = f >> 1;
    int kc = f & 1;
    int u   = w * 16 + c;
    int row = g * 256 + u;
    int k0  = kc * 128 + kb * 32 + d * 4;
    const float* src = Whh + (size_t)row * HID + k0;
    uint32_t p = pack4_e4m3(src[0] * 16.0f, src[1] * 16.0f,
                            src[2] * 16.0f, src[3] * 16.0f);
    wfragP[(size_t)gid] = p;

    if (gid < G4) bias[gid] = bih[gid] + bhh[gid];
}

// ---------- features: conv mean + RBF kernel sim ----------
__global__ void feat_kernel(const float* __restrict__ x,
                            const float* __restrict__ conv_w,
                            const float* __restrict__ conv_b,
                            float* __restrict__ convf,
                            float* __restrict__ ksim) {
    int b = blockIdx.x, t = threadIdx.x;  // 256 threads
    const float4* xb = (const float4*)(x + (size_t)b * SEQ * IN_DIM);
    float cw0 = conv_w[0], cw1 = conv_w[1], cw2 = conv_w[2], cw3 = conv_w[3];
    float cb = conv_b[0];
    float s_sig = 0.f, s_sq = 0.f;
#pragma unroll
    for (int k = 0; k < 8; ++k) {
        int s = t + k * 256;
        float4 v = xb[s];
        float d = v.x * cw0 + v.y * cw1 + v.z * cw2 + v.w * cw3 + cb;
        s_sig += sigmoidf_(d);
        s_sq  += v.x * v.x + v.y * v.y + v.z * v.z + v.w * v.w;
    }
    __shared__ float sA[256], sB[256];
    sA[t] = s_sig; sB[t] = s_sq;
    __syncthreads();
    for (int off = 128; off > 0; off >>= 1) {
        if (t < off) { sA[t] += sA[t + off]; sB[t] += sB[t + off]; }
        __syncthreads();
    }
    if (t == 0) {
        convf[b] = sA[0] * (1.0f / 2048.0f);
        ksim[b]  = __expf(-sB[0]);
    }
}

// ---------- LSTM recurrence: MX-fp8 MFMA, 16 waves (4/SIMD) ----------
// 1024 threads = 16 waves, 1 sample/block. Wave w owns units [w*16,(w+1)*16):
// 4 tiles (one per gate) x 2 k-chunks = 8 mfma_scale_f32_16x16x128_f8f6f4
// per step; weights = 8 v8i32 = 64 regs/wave, register-resident.
// Per-SIMD MFMA issue = 4 waves x 8 x ~34.6 = ~1107 cyc (same floor as R6)
// but 4 waves/SIMD (vs R6's 2) hide ds_read/epilogue/barrier stalls -- the
// measured ~1500 cyc/step stall term.
// Point fixes vs R6: x[s+1] loaded at loop TOP (global latency under MFMA);
// xz LDS reads issued BEFORE the MFMA block; acc seeded by zero-C MFMA;
// 1-unit epilogue per lane. ONE barrier per step.
#define HB0_DW  0
#define HB1_DW  64
#define XZ0_DW  128
#define XZ1_DW  640
#define SMEM_DW 1152   // 4608 B

__global__ __launch_bounds__(1024, 4)
void recur_kernel(const float* __restrict__ x,
                  const float* __restrict__ Wih,
                  const uint32_t* __restrict__ wfragP,
                  const float* __restrict__ bias,
                  float* __restrict__ h_out) {
    extern __shared__ uint32_t smem[];
    uint32_t* hb0 = smem + HB0_DW;            // 256 fp8 bytes
    uint32_t* hb1 = smem + HB1_DW;
    __half* xz0 = (__half*)(smem + XZ0_DW);   // 1024 f16
    __half* xz1 = (__half*)(smem + XZ1_DW);

    const int b = blockIdx.x;
    const int t = threadIdx.x;
    const int lane = t & 63;
    const int w = t >> 6;        // 0..15
    const int cl = lane & 15;
    const int grp = lane >> 4;
    const int uA = w * 16 + cl;

    // all 8 weight fragments -> registers (64 VGPR/AGPR)
    U328 rf[8];
    {
        const uint32_t* base = wfragP + (size_t)w * 4096 + (size_t)lane * 8;
#pragma unroll
        for (int f = 0; f < 8; ++f) {
            rf[f].q[0] = *(const uint4*)(base + f * 512);
            rf[f].q[1] = *(const uint4*)(base + f * 512 + 4);
        }
    }
#pragma unroll
    for (int f = 0; f < 8; ++f) asm volatile("" : "+v"(rf[f].v));

    if (t < 64) hb0[t] = 0u;   // h = 0 (fp8 zeros)

    // xz pipeline: this thread owns gate-row t
    const float4 wr = ((const float4*)Wih)[t];
    const float bs = bias[t];
    const float4* xb = (const float4*)(x + (size_t)b * SEQ * IN_DIM);

    {   // xz(0)
        const float4 x0 = xb[0];
        xz0[t] = __float2half_rn(bs + x0.x*wr.x + x0.y*wr.y + x0.z*wr.z + x0.w*wr.w);
    }

    float cA = 0.f, hA = 0.f;

    __syncthreads();

    uint32_t* hr = hb0; uint32_t* hw = hb1;
    __half* xzr = xz0; __half* xzw = xz1;

    for (int s = 0; s < SEQ; ++s) {
        // ---- issue long-latency loads first ----
        const int sn = (s + 1 < SEQ) ? s + 1 : SEQ - 1;
        const float4 xn = xb[sn];                 // global; hides under MFMA

        const float xzi = __half2float(xzr[uA]);
        const float xzf = __half2float(xzr[256 + uA]);
        const float xzg = __half2float(xzr[512 + uA]);
        const float xzo = __half2float(xzr[768 + uA]);

        const unsigned char* hrb = (const unsigned char*)hr;
        U328 hk0, hk1;
        hk0.q[0] = *(const uint4*)(hrb + grp * 32);
        hk0.q[1] = *(const uint4*)(hrb + grp * 32 + 16);
        hk1.q[0] = *(const uint4*)(hrb + 128 + grp * 32);
        hk1.q[1] = *(const uint4*)(hrb + 128 + grp * 32 + 16);

        // ---- 8 MFMA: 4 gate-tiles x 2 k-chunks, zero-C seed ----
        const f32x4 z4 = (f32x4){0.f, 0.f, 0.f, 0.f};
        f32x4 a0 = __builtin_amdgcn_mfma_scale_f32_16x16x128_f8f6f4(
            hk0.v, rf[0].v, z4, 0, 0, 0, SCALE_H, 0, SCALE_W);
        f32x4 a1 = __builtin_amdgcn_mfma_scale_f32_16x16x128_f8f6f4(
            hk0.v, rf[2].v, z4, 0, 0, 0, SCALE_H, 0, SCALE_W);
        f32x4 a2 = __builtin_amdgcn_mfma_scale_f32_16x16x128_f8f6f4(
            hk0.v, rf[4].v, z4, 0, 0, 0, SCALE_H, 0, SCALE_W);
        f32x4 a3 = __builtin_amdgcn_mfma_scale_f32_16x16x128_f8f6f4(
            hk0.v, rf[6].v, z4, 0, 0, 0, SCALE_H, 0, SCALE_W);
        a0 = __builtin_amdgcn_mfma_scale_f32_16x16x128_f8f6f4(
            hk1.v, rf[1].v, a0, 0, 0, 0, SCALE_H, 0, SCALE_W);
        a1 = __builtin_amdgcn_mfma_scale_f32_16x16x128_f8f6f4(
            hk1.v, rf[3].v, a1, 0, 0, 0, SCALE_H, 0, SCALE_W);
        a2 = __builtin_amdgcn_mfma_scale_f32_16x16x128_f8f6f4(
            hk1.v, rf[5].v, a2, 0, 0, 0, SCALE_H, 0, SCALE_W);
        a3 = __builtin_amdgcn_mfma_scale_f32_16x16x128_f8f6f4(
            hk1.v, rf[7].v, a3, 0, 0, 0, SCALE_H, 0, SCALE_W);

        // ---- in-lane epilogue: 4 gates of unit uA ----
        const float zi = a0[0] + xzi;
        const float zf = a1[0] + xzf;
        const float zg = a2[0] + xzg;
        const float zo = a3[0] + xzo;
        cA = sigmoidf_(zf) * cA + sigmoidf_(zi) * tanhf_(zg);
        hA = sigmoidf_(zo) * tanhf_(cA);

        // xz(s+1) using prefetched xn
        xzw[t] = __float2half_rn(bs + xn.x*wr.x + xn.y*wr.y + xn.z*wr.z + xn.w*wr.w);
        // h(s+1) as fp8: one row-group copy writes
        if (lane < 16) {
            ((unsigned char*)hw)[uA] = (unsigned char)enc_e4m3(hA);
        }
        __syncthreads();   // the ONLY barrier per step
        { uint32_t* tp = hr; hr = hw; hw = tp; }
        { __half* tp = xzr; xzr = xzw; xzw = tp; }
    }

    if (lane < 16) h_out[b * HID + uA] = hA;
}

// ---------- head: fc + relu + out + softmax ----------
__global__ void head_kernel(const float* __restrict__ fc_w,
                            const float* __restrict__ fc_b,
                            const float* __restrict__ out_w,
                            const float* __restrict__ out_b,
                            const float* __restrict__ convf,
                            const float* __restrict__ ksim,
                            const float* __restrict__ h_out,
                            float* __restrict__ out) {
    int b = blockIdx.x, j = threadIdx.x;  // 256 threads
    const float* hrow = h_out + b * HID;
    const float* w = fc_w + j * (HID + 2);
    float acc = fc_b[j] + w[0] * convf[b] + w[HID + 1] * ksim[b];
#pragma unroll 8
    for (int k = 0; k < HID; ++k) acc += w[1 + k] * hrow[k];
    float hid = fmaxf(acc, 0.f);
    __shared__ float r0[256], r1[256];
    r0[j] = hid * out_w[j];
    r1[j] = hid * out_w[HID + j];
    __syncthreads();
    for (int off = 128; off > 0; off >>= 1) {
        if (j < off) { r0[j] += r0[j + off]; r1[j] += r1[j + off]; }
        __syncthreads();
    }
    if (j == 0) {
        float l0 = r0[0] + out_b[0];
        float l1 = r1[0] + out_b[1];
        float m = fmaxf(l0, l1);
        float e0 = __expf(l0 - m), e1 = __expf(l1 - m);
        float inv = 1.0f / (e0 + e1);
        out[b * 2 + 0] = e0 * inv;
        out[b * 2 + 1] = e1 * inv;
    }
}

// ---------- launch ----------
extern "C" void kernel_launch(void* const* d_in, const int* in_sizes, int n_in,
                              void* d_out, int out_size, void* d_ws, size_t ws_size,
                              hipStream_t stream) {
    const float* x      = (const float*)d_in[0];
    const float* conv_w = (const float*)d_in[1];
    const float* conv_b = (const float*)d_in[2];
    const float* Wih    = (const float*)d_in[3];
    const float* Whh    = (const float*)d_in[4];
    const float* bih    = (const float*)d_in[5];
    const float* bhh    = (const float*)d_in[6];
    const float* fcw    = (const float*)d_in[7];
    const float* fcb    = (const float*)d_in[8];
    const float* outw   = (const float*)d_in[9];
    const float* outb   = (const float*)d_in[10];
    float* out = (float*)d_out;

    uint8_t* ws = (uint8_t*)d_ws;
    uint32_t* wfragP = (uint32_t*)ws;
    float* bias  = (float*)(ws + OFF_BIAS);
    float* convf = (float*)(ws + OFF_CONVF);
    float* ksim  = (float*)(ws + OFF_KSIM);
    float* h_out = (float*)(ws + OFF_HOUT);

    prep_kernel<<<256, 256, 0, stream>>>(Whh, bih, bhh, wfragP, bias);
    feat_kernel<<<BATCH, 256, 0, stream>>>(x, conv_w, conv_b, convf, ksim);

    const size_t smem_bytes = (size_t)SMEM_DW * 4;  // 4608 B
    recur_kernel<<<BATCH, 1024, smem_bytes, stream>>>(x, Wih, wfragP, bias, h_out);

    head_kernel<<<BATCH, 256, 0, stream>>>(fcw, fcb, outw, outb, convf, ksim, h_out, out);
}